// Round 1
// baseline (1160.016 us; speedup 1.0000x reference)
//
#include <hip/hip_runtime.h>
#include <math.h>

// Problem constants
#define B_    4
#define LQ_   1024
#define LKV_  4096
#define DM    512    // model dim
#define NH    4
#define HD_   128    // head dim

// ---------------------------------------------------------------------------
// GEMM: Y[N,512] = X[N,512] @ W[512,512]^T + bias[512]
// 128x128 tile per 256-thread block, 8x8 per thread, k-tile 16.
// ---------------------------------------------------------------------------
__global__ __launch_bounds__(256) void proj_gemm(
    const float* __restrict__ X,
    const float* __restrict__ W,
    const float* __restrict__ bias,
    float* __restrict__ Y)
{
  __shared__ float Xs[16][132];   // [k][row], pad 132 to break b128 bank groups
  __shared__ float Ws[16][132];   // [k][col]

  const int tid  = threadIdx.x;
  const int tx   = tid & 15;      // col group
  const int ty   = tid >> 4;      // row group
  const int row0 = blockIdx.x * 128;
  const int col0 = blockIdx.y * 128;

  float acc[8][8];
#pragma unroll
  for (int a = 0; a < 8; ++a)
#pragma unroll
    for (int b = 0; b < 8; ++b) acc[a][b] = 0.f;

  for (int k0 = 0; k0 < 512; k0 += 16) {
#pragma unroll
    for (int i = 0; i < 2; ++i) {
      int f  = i * 256 + tid;       // 0..511
      int r  = f >> 2;              // 0..127
      int kq = (f & 3) * 4;         // 0,4,8,12
      float4 xv = *(const float4*)(X + (size_t)(row0 + r) * 512 + k0 + kq);
      float4 wv = *(const float4*)(W + (size_t)(col0 + r) * 512 + k0 + kq);
      Xs[kq + 0][r] = xv.x; Xs[kq + 1][r] = xv.y;
      Xs[kq + 2][r] = xv.z; Xs[kq + 3][r] = xv.w;
      Ws[kq + 0][r] = wv.x; Ws[kq + 1][r] = wv.y;
      Ws[kq + 2][r] = wv.z; Ws[kq + 3][r] = wv.w;
    }
    __syncthreads();
#pragma unroll
    for (int kk = 0; kk < 16; ++kk) {
      float xa[8], wb[8];
#pragma unroll
      for (int p = 0; p < 2; ++p) {
        float4 xv = *(const float4*)&Xs[kk][ty * 8 + p * 4];
        xa[p * 4 + 0] = xv.x; xa[p * 4 + 1] = xv.y;
        xa[p * 4 + 2] = xv.z; xa[p * 4 + 3] = xv.w;
        float4 wv = *(const float4*)&Ws[kk][tx * 4 + p * 64];
        wb[p * 4 + 0] = wv.x; wb[p * 4 + 1] = wv.y;
        wb[p * 4 + 2] = wv.z; wb[p * 4 + 3] = wv.w;
      }
#pragma unroll
      for (int a = 0; a < 8; ++a)
#pragma unroll
        for (int b = 0; b < 8; ++b) acc[a][b] += xa[a] * wb[b];
    }
    __syncthreads();
  }

  // rows ty*8..+7 ; cols {col0+tx*4..+3} and {col0+64+tx*4..+3}
#pragma unroll
  for (int a = 0; a < 8; ++a) {
    int r = row0 + ty * 8 + a;
#pragma unroll
    for (int p = 0; p < 2; ++p) {
      int c = col0 + tx * 4 + p * 64;
      float4 ov;
      ov.x = acc[a][p * 4 + 0] + bias[c + 0];
      ov.y = acc[a][p * 4 + 1] + bias[c + 1];
      ov.z = acc[a][p * 4 + 2] + bias[c + 2];
      ov.w = acc[a][p * 4 + 3] + bias[c + 3];
      *(float4*)(Y + (size_t)r * 512 + c) = ov;
    }
  }
}

// ---------------------------------------------------------------------------
// Flash attention (fp32, online softmax). One block per (b, h, 32 q rows).
// Q/K/V are [B*L, 512] with head h at columns h*128..h*128+127.
// ---------------------------------------------------------------------------
__global__ __launch_bounds__(256) void flash_attn(
    const float* __restrict__ Q,
    const float* __restrict__ K,
    const float* __restrict__ V,
    float* __restrict__ CTX)
{
  __shared__ float Qs[32][132];
  __shared__ float Ks[32][132];
  __shared__ float Vs[32][128];
  __shared__ float Ss[32][33];
  __shared__ float mS[32], lS[32], aS[32];

  const int tid = threadIdx.x;
  const int qt  = blockIdx.x & 31;     // LQ/32 = 32 q tiles
  const int bh  = blockIdx.x >> 5;
  const int h   = bh & 3;
  const int b   = bh >> 2;
  const float scale = 0.08838834764831845f;  // 1/sqrt(128)

  const float* Qg = Q + (size_t)(b * LQ_ + qt * 32) * DM + h * HD_;
  const float* Kg = K + (size_t)(b * LKV_) * DM + h * HD_;
  const float* Vg = V + (size_t)(b * LKV_) * DM + h * HD_;

  // Load Q tile (32x128) via float4
#pragma unroll
  for (int i = 0; i < 4; ++i) {
    int f  = i * 256 + tid;       // 0..1023
    int r  = f >> 5;              // 0..31
    int d4 = (f & 31) * 4;
    *(float4*)&Qs[r][d4] = *(const float4*)(Qg + (size_t)r * DM + d4);
  }
  if (tid < 32) { mS[tid] = -INFINITY; lS[tid] = 0.f; }

  const int d4o = (tid & 31) * 4;     // this thread's d slice
  const int rq  = tid >> 5;           // 0..7 : rows 8i+rq
  float4 o[4];
#pragma unroll
  for (int i = 0; i < 4; ++i) o[i] = make_float4(0.f, 0.f, 0.f, 0.f);

  __syncthreads();

  for (int kt = 0; kt < LKV_ / 32; ++kt) {
    // stage K,V tiles (32x128 each)
#pragma unroll
    for (int i = 0; i < 4; ++i) {
      int f  = i * 256 + tid;
      int r  = f >> 5;
      int d4 = (f & 31) * 4;
      *(float4*)&Ks[r][d4] = *(const float4*)(Kg + (size_t)(kt * 32 + r) * DM + d4);
      *(float4*)&Vs[r][d4] = *(const float4*)(Vg + (size_t)(kt * 32 + r) * DM + d4);
    }
    __syncthreads();

    // S = scale * Q K^T : thread computes rows {2*(t>>4),+1} x cols {t&15, +16}
    {
      const int r0 = (tid >> 4) * 2;
      const int c0 = tid & 15;
      float a00 = 0.f, a01 = 0.f, a10 = 0.f, a11 = 0.f;
#pragma unroll
      for (int d = 0; d < HD_; d += 4) {
        float4 q0 = *(const float4*)&Qs[r0][d];
        float4 q1 = *(const float4*)&Qs[r0 + 1][d];
        float4 k0 = *(const float4*)&Ks[c0][d];
        float4 k1 = *(const float4*)&Ks[c0 + 16][d];
        a00 += q0.x * k0.x + q0.y * k0.y + q0.z * k0.z + q0.w * k0.w;
        a01 += q0.x * k1.x + q0.y * k1.y + q0.z * k1.z + q0.w * k1.w;
        a10 += q1.x * k0.x + q1.y * k0.y + q1.z * k0.z + q1.w * k0.w;
        a11 += q1.x * k1.x + q1.y * k1.y + q1.z * k1.z + q1.w * k1.w;
      }
      Ss[r0][c0]          = a00 * scale;
      Ss[r0][c0 + 16]     = a01 * scale;
      Ss[r0 + 1][c0]      = a10 * scale;
      Ss[r0 + 1][c0 + 16] = a11 * scale;
    }
    __syncthreads();

    // online softmax (one lane per q row)
    if (tid < 32) {
      const int r = tid;
      float m_old = mS[r];
      float mx = m_old;
#pragma unroll
      for (int j = 0; j < 32; ++j) mx = fmaxf(mx, Ss[r][j]);
      float alpha = __expf(m_old - mx);   // exp(-inf)=0 on first tile
      float sum = 0.f;
#pragma unroll
      for (int j = 0; j < 32; ++j) {
        float p = __expf(Ss[r][j] - mx);
        Ss[r][j] = p;
        sum += p;
      }
      mS[r] = mx;
      lS[r] = lS[r] * alpha + sum;
      aS[r] = alpha;
    }
    __syncthreads();

    // O = O*alpha + P V  (thread: fixed d4o, rows 8i+rq)
#pragma unroll
    for (int i = 0; i < 4; ++i) {
      float a = aS[8 * i + rq];
      o[i].x *= a; o[i].y *= a; o[i].z *= a; o[i].w *= a;
    }
#pragma unroll 8
    for (int j = 0; j < 32; ++j) {
      float4 v = *(const float4*)&Vs[j][d4o];
#pragma unroll
      for (int i = 0; i < 4; ++i) {
        float s = Ss[8 * i + rq][j];
        o[i].x += s * v.x; o[i].y += s * v.y;
        o[i].z += s * v.z; o[i].w += s * v.w;
      }
    }
    __syncthreads();
  }

  // normalize and write ctx
  float* Cg = CTX + (size_t)(b * LQ_ + qt * 32) * DM + h * HD_;
#pragma unroll
  for (int i = 0; i < 4; ++i) {
    int r = 8 * i + rq;
    float inv = 1.f / lS[r];
    float4 ov = o[i];
    ov.x *= inv; ov.y *= inv; ov.z *= inv; ov.w *= inv;
    *(float4*)(Cg + (size_t)r * DM + d4o) = ov;
  }
}

// ---------------------------------------------------------------------------
extern "C" void kernel_launch(void* const* d_in, const int* in_sizes, int n_in,
                              void* d_out, int out_size, void* d_ws, size_t ws_size,
                              hipStream_t stream) {
  const float* x   = (const float*)d_in[0];
  const float* enc = (const float*)d_in[1];
  const float* Wq  = (const float*)d_in[2];
  const float* Wk  = (const float*)d_in[3];
  const float* Wv  = (const float*)d_in[4];
  const float* bq  = (const float*)d_in[5];
  const float* bk  = (const float*)d_in[6];
  const float* bv  = (const float*)d_in[7];
  const float* Wo  = (const float*)d_in[8];
  const float* bo  = (const float*)d_in[9];
  float* out = (float*)d_out;

  // workspace layout (floats): Q[4096*512] K[16384*512] V[16384*512] CTX[4096*512]
  float* ws  = (float*)d_ws;
  float* Qp  = ws;
  float* Kp  = Qp + (size_t)B_ * LQ_ * DM;      // +2,097,152
  float* Vp  = Kp + (size_t)B_ * LKV_ * DM;     // +8,388,608
  float* CTX = Vp + (size_t)B_ * LKV_ * DM;     // +8,388,608   (total 80 MB)

  dim3 blk(256);
  proj_gemm<<<dim3((B_ * LQ_) / 128, 4), blk, 0, stream>>>(x,   Wq, bq, Qp);
  proj_gemm<<<dim3((B_ * LKV_) / 128, 4), blk, 0, stream>>>(enc, Wk, bk, Kp);
  proj_gemm<<<dim3((B_ * LKV_) / 128, 4), blk, 0, stream>>>(enc, Wv, bv, Vp);
  flash_attn<<<dim3(B_ * NH * (LQ_ / 32)), blk, 0, stream>>>(Qp, Kp, Vp, CTX);
  proj_gemm<<<dim3((B_ * LQ_) / 128, 4), blk, 0, stream>>>(CTX, Wo, bo, out);
}

// Round 2
// 710.829 us; speedup vs baseline: 1.6319x; 1.6319x over previous
//
#include <hip/hip_runtime.h>
#include <math.h>

// Problem constants
#define B_    4
#define LQ_   1024
#define LKV_  4096
#define DM    512    // model dim
#define NH    4
#define HD_   128    // head dim

typedef _Float16 half8   __attribute__((ext_vector_type(8)));
typedef _Float16 half4_t __attribute__((ext_vector_type(4)));
typedef float    floatx4 __attribute__((ext_vector_type(4)));

#define MFMA16(a, b, c) __builtin_amdgcn_mfma_f32_16x16x32_f16((a), (b), (c), 0, 0, 0)

// ---------------------------------------------------------------------------
// GEMM: Y[N,512] = (X[N,512] @ W[512,512]^T + bias) * scale
// fp32 compute (verified round 1); output fp32 or f16 per template.
// ---------------------------------------------------------------------------
template<bool F16OUT>
__global__ __launch_bounds__(256) void proj_gemm(
    const float* __restrict__ X,
    const float* __restrict__ W,
    const float* __restrict__ bias,
    void* __restrict__ Yv,
    float scale)
{
  __shared__ float Xs[16][132];
  __shared__ float Ws[16][132];

  const int tid  = threadIdx.x;
  const int tx   = tid & 15;
  const int ty   = tid >> 4;
  const int row0 = blockIdx.x * 128;
  const int col0 = blockIdx.y * 128;

  float acc[8][8];
#pragma unroll
  for (int a = 0; a < 8; ++a)
#pragma unroll
    for (int b = 0; b < 8; ++b) acc[a][b] = 0.f;

  for (int k0 = 0; k0 < 512; k0 += 16) {
#pragma unroll
    for (int i = 0; i < 2; ++i) {
      int f  = i * 256 + tid;
      int r  = f >> 2;
      int kq = (f & 3) * 4;
      float4 xv = *(const float4*)(X + (size_t)(row0 + r) * 512 + k0 + kq);
      float4 wv = *(const float4*)(W + (size_t)(col0 + r) * 512 + k0 + kq);
      Xs[kq + 0][r] = xv.x; Xs[kq + 1][r] = xv.y;
      Xs[kq + 2][r] = xv.z; Xs[kq + 3][r] = xv.w;
      Ws[kq + 0][r] = wv.x; Ws[kq + 1][r] = wv.y;
      Ws[kq + 2][r] = wv.z; Ws[kq + 3][r] = wv.w;
    }
    __syncthreads();
#pragma unroll
    for (int kk = 0; kk < 16; ++kk) {
      float xa[8], wb[8];
#pragma unroll
      for (int p = 0; p < 2; ++p) {
        float4 xv = *(const float4*)&Xs[kk][ty * 8 + p * 4];
        xa[p * 4 + 0] = xv.x; xa[p * 4 + 1] = xv.y;
        xa[p * 4 + 2] = xv.z; xa[p * 4 + 3] = xv.w;
        float4 wv = *(const float4*)&Ws[kk][tx * 4 + p * 64];
        wb[p * 4 + 0] = wv.x; wb[p * 4 + 1] = wv.y;
        wb[p * 4 + 2] = wv.z; wb[p * 4 + 3] = wv.w;
      }
#pragma unroll
      for (int a = 0; a < 8; ++a)
#pragma unroll
        for (int b = 0; b < 8; ++b) acc[a][b] += xa[a] * wb[b];
    }
    __syncthreads();
  }

#pragma unroll
  for (int a = 0; a < 8; ++a) {
    int r = row0 + ty * 8 + a;
#pragma unroll
    for (int p = 0; p < 2; ++p) {
      int c = col0 + tx * 4 + p * 64;
      float v0 = (acc[a][p * 4 + 0] + bias[c + 0]) * scale;
      float v1 = (acc[a][p * 4 + 1] + bias[c + 1]) * scale;
      float v2 = (acc[a][p * 4 + 2] + bias[c + 2]) * scale;
      float v3 = (acc[a][p * 4 + 3] + bias[c + 3]) * scale;
      if (F16OUT) {
        half4_t hv;
        hv[0] = (_Float16)v0; hv[1] = (_Float16)v1;
        hv[2] = (_Float16)v2; hv[3] = (_Float16)v3;
        *(half4_t*)((_Float16*)Yv + (size_t)r * 512 + c) = hv;
      } else {
        float4 ov; ov.x = v0; ov.y = v1; ov.z = v2; ov.w = v3;
        *(float4*)((float*)Yv + (size_t)r * 512 + c) = ov;
      }
    }
  }
}

// ---------------------------------------------------------------------------
// Transpose V per head: Vh [B*LKV, 512] f16 -> Vt [B*NH*HD, LKV] f16 (d-major)
// 64(kv) x 64(d) tiles through LDS.
// ---------------------------------------------------------------------------
__global__ __launch_bounds__(256) void transpose_v(
    const _Float16* __restrict__ Vh,
    _Float16* __restrict__ Vt)
{
  __shared__ _Float16 Ts[64][74];
  const int tid = threadIdx.x;
  const int kvt = blockIdx.x;     // 64 tiles of 64 kv
  const int dt  = blockIdx.y;     // 2 tiles of 64 d
  const int bh  = blockIdx.z;     // 16
  const int b = bh >> 2, h = bh & 3;

#pragma unroll
  for (int i = 0; i < 2; ++i) {
    int f  = i * 256 + tid;        // 0..511
    int r  = f >> 3;               // kv row 0..63
    int c8 = (f & 7) * 8;          // d offset
    half8 v = *(const half8*)(Vh + (size_t)(b * LKV_ + kvt * 64 + r) * DM
                              + h * HD_ + dt * 64 + c8);
    union { half8 h; unsigned int u[4]; } cv; cv.h = v;
    *(unsigned int*)&Ts[r][c8 + 0] = cv.u[0];
    *(unsigned int*)&Ts[r][c8 + 2] = cv.u[1];
    *(unsigned int*)&Ts[r][c8 + 4] = cv.u[2];
    *(unsigned int*)&Ts[r][c8 + 6] = cv.u[3];
  }
  __syncthreads();
#pragma unroll
  for (int i = 0; i < 2; ++i) {
    int g  = i * 256 + tid;
    int d  = g >> 3;               // 0..63
    int k8 = (g & 7) * 8;          // kv offset
    half8 ov;
#pragma unroll
    for (int j = 0; j < 8; ++j) ov[j] = Ts[k8 + j][d];
    *(half8*)(Vt + (size_t)(bh * HD_ + dt * 64 + d) * LKV_ + kvt * 64 + k8) = ov;
  }
}

// ---------------------------------------------------------------------------
// Flash attention, f16 MFMA 16x16x32. Block = (b,h,64 q rows), 4 waves x 16 q.
// Q pre-scaled by 1/sqrt(HD). KV tile = 64.
// A-frag: A[m=lane&15][k=quad*8+j]; B-frag: B[k=quad*8+j][n=lane&15];
// C/D:    [row=quad*4+reg][col=lane&15]   (m89/m91-verified layouts)
// ---------------------------------------------------------------------------
__global__ __launch_bounds__(256) void flash_mfma(
    const _Float16* __restrict__ Qh,   // [B*LQ, 512], pre-scaled
    const _Float16* __restrict__ Kh,   // [B*LKV, 512]
    const _Float16* __restrict__ Vtg,  // [B*NH*HD, LKV], d-major
    float* __restrict__ CTX)           // [B*LQ, 512] fp32
{
  __shared__ _Float16 Ks[64][136];     // Q stage, then K tiles (row-major in d)
  __shared__ _Float16 Vs[128][72];     // V tile, d-major: [d][kv]
  __shared__ _Float16 Ps[4][16][72];   // per-wave P (16 q rows x 64 kv)

  const int tid  = threadIdx.x;
  const int lane = tid & 63;
  const int w    = tid >> 6;
  const int n16  = lane & 15;
  const int quad = lane >> 4;

  const int qt = blockIdx.x & 15;      // 16 q-tiles of 64
  const int bh = blockIdx.x >> 4;
  const int h  = bh & 3, b = bh >> 2;

  const _Float16* Qg = Qh + (size_t)(b * LQ_ + qt * 64) * DM + h * HD_;
  const _Float16* Kg = Kh + (size_t)(b * LKV_) * DM + h * HD_;
  const _Float16* Vg = Vtg + (size_t)(bh * HD_) * LKV_;

  // stage Q (64x128) into Ks, pull A-frags to registers
#pragma unroll
  for (int i = 0; i < 4; ++i) {
    int f = i * 256 + tid;
    int r = f >> 4, c8 = (f & 15) * 8;
    *(half8*)&Ks[r][c8] = *(const half8*)(Qg + (size_t)r * DM + c8);
  }
  __syncthreads();
  half8 qf[4];
#pragma unroll
  for (int kc = 0; kc < 4; ++kc)
    qf[kc] = *(const half8*)&Ks[w * 16 + n16][kc * 32 + quad * 8];
  __syncthreads();

  floatx4 o[8];
#pragma unroll
  for (int vb = 0; vb < 8; ++vb) o[vb] = (floatx4){0.f, 0.f, 0.f, 0.f};
  float m_i[4] = {-INFINITY, -INFINITY, -INFINITY, -INFINITY};
  float l_i[4] = {0.f, 0.f, 0.f, 0.f};

  for (int kt = 0; kt < LKV_ / 64; ++kt) {
    // stage K tile (64 kv x 128 d) and V tile (128 d x 64 kv)
#pragma unroll
    for (int i = 0; i < 4; ++i) {
      int f = i * 256 + tid;
      int r = f >> 4, c8 = (f & 15) * 8;
      *(half8*)&Ks[r][c8] = *(const half8*)(Kg + (size_t)(kt * 64 + r) * DM + c8);
    }
#pragma unroll
    for (int i = 0; i < 4; ++i) {
      int f = i * 256 + tid;
      int d = f >> 3, kv8 = (f & 7) * 8;
      *(half8*)&Vs[d][kv8] = *(const half8*)(Vg + (size_t)d * LKV_ + kt * 64 + kv8);
    }
    __syncthreads();

    // S[16 x 64] per wave = Q Kt
    floatx4 s[4];
#pragma unroll
    for (int cb = 0; cb < 4; ++cb) {
      s[cb] = (floatx4){0.f, 0.f, 0.f, 0.f};
#pragma unroll
      for (int kc = 0; kc < 4; ++kc) {
        half8 kf = *(const half8*)&Ks[cb * 16 + n16][kc * 32 + quad * 8];
        s[cb] = MFMA16(qf[kc], kf, s[cb]);
      }
    }

    // online softmax: rows r = quad*4 + reg, reduce across 16 lanes of quad
    float alpha[4], rs[4];
#pragma unroll
    for (int r = 0; r < 4; ++r) {
      float m0 = fmaxf(fmaxf(s[0][r], s[1][r]), fmaxf(s[2][r], s[3][r]));
#pragma unroll
      for (int off = 1; off < 16; off <<= 1) m0 = fmaxf(m0, __shfl_xor(m0, off));
      float mn = fmaxf(m_i[r], m0);
      alpha[r] = __expf(m_i[r] - mn);   // first tile: exp(-inf) = 0
      m_i[r] = mn;
      rs[r] = 0.f;
    }
#pragma unroll
    for (int cb = 0; cb < 4; ++cb) {
#pragma unroll
      for (int r = 0; r < 4; ++r) {
        float p = __expf(s[cb][r] - m_i[r]);
        rs[r] += p;
        Ps[w][quad * 4 + r][cb * 16 + n16] = (_Float16)p;
      }
    }
#pragma unroll
    for (int r = 0; r < 4; ++r) {
      float t = rs[r];
#pragma unroll
      for (int off = 1; off < 16; off <<= 1) t += __shfl_xor(t, off);
      l_i[r] = l_i[r] * alpha[r] + t;
#pragma unroll
      for (int vb = 0; vb < 8; ++vb) o[vb][r] *= alpha[r];
    }

    // O += P V   (P from per-wave LDS buffer; intra-wave, no barrier needed)
    half8 pf[2];
#pragma unroll
    for (int kc = 0; kc < 2; ++kc)
      pf[kc] = *(const half8*)&Ps[w][n16][kc * 32 + quad * 8];
#pragma unroll
    for (int vb = 0; vb < 8; ++vb) {
#pragma unroll
      for (int kc = 0; kc < 2; ++kc) {
        half8 vf = *(const half8*)&Vs[vb * 16 + n16][kc * 32 + quad * 8];
        o[vb] = MFMA16(pf[kc], vf, o[vb]);
      }
    }
    __syncthreads();
  }

  // normalize, write ctx (fp32)
  float* Cg = CTX + (size_t)(b * LQ_ + qt * 64 + w * 16) * DM + h * HD_;
#pragma unroll
  for (int r = 0; r < 4; ++r) {
    float inv = 1.f / l_i[r];
#pragma unroll
    for (int vb = 0; vb < 8; ++vb)
      Cg[(size_t)(quad * 4 + r) * DM + vb * 16 + n16] = o[vb][r] * inv;
  }
}

// ---------------------------------------------------------------------------
extern "C" void kernel_launch(void* const* d_in, const int* in_sizes, int n_in,
                              void* d_out, int out_size, void* d_ws, size_t ws_size,
                              hipStream_t stream) {
  const float* x   = (const float*)d_in[0];
  const float* enc = (const float*)d_in[1];
  const float* Wq  = (const float*)d_in[2];
  const float* Wk  = (const float*)d_in[3];
  const float* Wv  = (const float*)d_in[4];
  const float* bq  = (const float*)d_in[5];
  const float* bk  = (const float*)d_in[6];
  const float* bv  = (const float*)d_in[7];
  const float* Wo  = (const float*)d_in[8];
  const float* bo  = (const float*)d_in[9];
  float* out = (float*)d_out;

  // workspace layout (bytes):
  //   Qh  f16 [4096 x 512]   =  4 MB @ 0
  //   Kh  f16 [16384 x 512]  = 16 MB @ 4 MB
  //   Vh  f16 [16384 x 512]  = 16 MB @ 20 MB
  //   Vtg f16 [2048 x 4096]  = 16 MB @ 36 MB
  //   CTX f32 [4096 x 512]   =  8 MB @ 52 MB   (total 60 MB)
  char* ws = (char*)d_ws;
  _Float16* Qh  = (_Float16*)(ws);
  _Float16* Kh  = (_Float16*)(ws + (4u << 20));
  _Float16* Vh  = (_Float16*)(ws + (20u << 20));
  _Float16* Vtg = (_Float16*)(ws + (36u << 20));
  float*    CTX = (float*)   (ws + (52u << 20));

  const float qscale = 0.08838834764831845f;  // 1/sqrt(128)

  dim3 blk(256);
  proj_gemm<true ><<<dim3(32, 4),  blk, 0, stream>>>(x,   Wq, bq, Qh, qscale);
  proj_gemm<true ><<<dim3(128, 4), blk, 0, stream>>>(enc, Wk, bk, Kh, 1.f);
  proj_gemm<true ><<<dim3(128, 4), blk, 0, stream>>>(enc, Wv, bv, Vh, 1.f);
  transpose_v<<<dim3(64, 2, 16), blk, 0, stream>>>(Vh, Vtg);
  flash_mfma<<<dim3(256), blk, 0, stream>>>(Qh, Kh, Vtg, CTX);
  proj_gemm<false><<<dim3(32, 4),  blk, 0, stream>>>(CTX, Wo, bo, out, 1.f);
}

// Round 3
// 260.718 us; speedup vs baseline: 4.4493x; 2.7264x over previous
//
#include <hip/hip_runtime.h>
#include <math.h>

// Problem constants
#define B_    4
#define LQ_   1024
#define LKV_  4096
#define DM    512    // model dim
#define NH    4
#define HD_   128    // head dim

typedef _Float16 half8   __attribute__((ext_vector_type(8)));
typedef _Float16 half4_t __attribute__((ext_vector_type(4)));
typedef float    floatx4 __attribute__((ext_vector_type(4)));

#define MFMA16(a, b, c) __builtin_amdgcn_mfma_f32_16x16x32_f16((a), (b), (c), 0, 0, 0)

// ---------------------------------------------------------------------------
// fp32 -> f16 casts
// ---------------------------------------------------------------------------
__global__ __launch_bounds__(256) void cast_f32_f16(
    const float* __restrict__ in, _Float16* __restrict__ out, int n4)
{
  int i = blockIdx.x * 256 + threadIdx.x;
  if (i < n4) {
    float4 v = *(const float4*)(in + (size_t)i * 4);
    half4_t h;
    h[0] = (_Float16)v.x; h[1] = (_Float16)v.y;
    h[2] = (_Float16)v.z; h[3] = (_Float16)v.w;
    *(half4_t*)(out + (size_t)i * 4) = h;
  }
}

__global__ __launch_bounds__(256) void cast_weights(
    const float* __restrict__ Wq, const float* __restrict__ Wk,
    const float* __restrict__ Wv, const float* __restrict__ Wo,
    _Float16* __restrict__ Wh)
{
  int i = (blockIdx.x * 256 + threadIdx.x) * 4;  // 0..1M-4, 1M = 4*512*512
  const float* src = (i < 524288) ? ((i < 262144) ? Wq : Wk)
                                  : ((i < 786432) ? Wv : Wo);
  int off = i & 262143;
  float4 v = *(const float4*)(src + off);
  half4_t h;
  h[0] = (_Float16)v.x; h[1] = (_Float16)v.y;
  h[2] = (_Float16)v.z; h[3] = (_Float16)v.w;
  *(half4_t*)(Wh + i) = h;
}

// ---------------------------------------------------------------------------
// f16 MFMA GEMM: Y[M,512] = (X[M,512] @ W[512,512]^T + bias) * scale
// Block 256 = 4 waves (2x2 of 64x64), tile 128x128, BK=64.
// A-frag: A[m=lane&15][k=quad*8+j]; B-frag: B[k=quad*8+j][n=lane&15]
// C/D:    row=quad*4+reg, col=lane&15      (round-2-verified layouts)
// ---------------------------------------------------------------------------
template<int F32OUT>
__global__ __launch_bounds__(256) void proj_mfma(
    const _Float16* __restrict__ X,
    const _Float16* __restrict__ W,    // [512 out][512 k] f16
    const float* __restrict__ bias,
    void* __restrict__ Yv, float scale)
{
  __shared__ _Float16 Xs[128][72];
  __shared__ _Float16 Ws[128][72];

  const int tid  = threadIdx.x;
  const int lane = tid & 63;
  const int w    = tid >> 6;
  const int n16  = lane & 15;
  const int quad = lane >> 4;
  const int wm   = (w & 1) * 64;
  const int wn   = (w >> 1) * 64;
  const int row0 = blockIdx.x * 128;
  const int col0 = blockIdx.y * 128;

  floatx4 acc[4][4];
#pragma unroll
  for (int a = 0; a < 4; ++a)
#pragma unroll
    for (int b = 0; b < 4; ++b) acc[a][b] = (floatx4){0.f, 0.f, 0.f, 0.f};

  for (int k0 = 0; k0 < 512; k0 += 64) {
#pragma unroll
    for (int i = 0; i < 4; ++i) {
      int c = i * 256 + tid;            // 0..1023
      int r = c >> 3, off = (c & 7) * 8;
      *(half8*)&Xs[r][off] = *(const half8*)(X + (size_t)(row0 + r) * 512 + k0 + off);
      *(half8*)&Ws[r][off] = *(const half8*)(W + (size_t)(col0 + r) * 512 + k0 + off);
    }
    __syncthreads();
#pragma unroll
    for (int kc = 0; kc < 2; ++kc) {
      half8 af[4], bf[4];
#pragma unroll
      for (int mb = 0; mb < 4; ++mb)
        af[mb] = *(const half8*)&Xs[wm + mb * 16 + n16][kc * 32 + quad * 8];
#pragma unroll
      for (int nb = 0; nb < 4; ++nb)
        bf[nb] = *(const half8*)&Ws[wn + nb * 16 + n16][kc * 32 + quad * 8];
#pragma unroll
      for (int mb = 0; mb < 4; ++mb)
#pragma unroll
        for (int nb = 0; nb < 4; ++nb)
          acc[mb][nb] = MFMA16(af[mb], bf[nb], acc[mb][nb]);
    }
    __syncthreads();
  }

#pragma unroll
  for (int mb = 0; mb < 4; ++mb) {
#pragma unroll
    for (int nb = 0; nb < 4; ++nb) {
#pragma unroll
      for (int r = 0; r < 4; ++r) {
        int row = row0 + wm + mb * 16 + quad * 4 + r;
        int col = col0 + wn + nb * 16 + n16;
        float v = (acc[mb][nb][r] + bias[col]) * scale;
        if (F32OUT) ((float*)Yv)[(size_t)row * 512 + col] = v;
        else ((_Float16*)Yv)[(size_t)row * 512 + col] = (_Float16)v;
      }
    }
  }
}

// ---------------------------------------------------------------------------
// Transpose V per head: Vh [B*LKV, 512] f16 -> Vt [B*NH*HD, LKV] f16 (d-major)
// ---------------------------------------------------------------------------
__global__ __launch_bounds__(256) void transpose_v(
    const _Float16* __restrict__ Vh,
    _Float16* __restrict__ Vt)
{
  __shared__ _Float16 Ts[64][74];
  const int tid = threadIdx.x;
  const int kvt = blockIdx.x;     // 64 tiles of 64 kv
  const int dt  = blockIdx.y;     // 2 tiles of 64 d
  const int bh  = blockIdx.z;     // 16
  const int b = bh >> 2, h = bh & 3;

#pragma unroll
  for (int i = 0; i < 2; ++i) {
    int f  = i * 256 + tid;
    int r  = f >> 3;
    int c8 = (f & 7) * 8;
    half8 v = *(const half8*)(Vh + (size_t)(b * LKV_ + kvt * 64 + r) * DM
                              + h * HD_ + dt * 64 + c8);
    union { half8 h; unsigned int u[4]; } cv; cv.h = v;
    *(unsigned int*)&Ts[r][c8 + 0] = cv.u[0];
    *(unsigned int*)&Ts[r][c8 + 2] = cv.u[1];
    *(unsigned int*)&Ts[r][c8 + 4] = cv.u[2];
    *(unsigned int*)&Ts[r][c8 + 6] = cv.u[3];
  }
  __syncthreads();
#pragma unroll
  for (int i = 0; i < 2; ++i) {
    int g  = i * 256 + tid;
    int d  = g >> 3;
    int k8 = (g & 7) * 8;
    half8 ov;
#pragma unroll
    for (int j = 0; j < 8; ++j) ov[j] = Ts[k8 + j][d];
    *(half8*)(Vt + (size_t)(bh * HD_ + dt * 64 + d) * LKV_ + kvt * 64 + k8) = ov;
  }
}

// ---------------------------------------------------------------------------
// Flash attention with split-KV. blockIdx.x = bh*4+split (64), blockIdx.y = qt (16).
// Each block: 64 q rows x 1024 kv (16 tiles of 64). Writes unnormalized
// partial O (f16) and (m,l) per row. LDS 35.8KB -> 4 blocks/CU.
// ---------------------------------------------------------------------------
__global__ __launch_bounds__(256, 4) void flash_mfma_split(
    const _Float16* __restrict__ Qh,   // [B*LQ, 512], pre-scaled
    const _Float16* __restrict__ Kh,   // [B*LKV, 512]
    const _Float16* __restrict__ Vtg,  // [B*NH*HD, LKV], d-major
    _Float16* __restrict__ Opart,      // [64][1024][128] f16 (xb-major)
    float* __restrict__ ml)            // [64][1024][2] f32
{
  __shared__ _Float16 Ks[64][136];     // K tiles; front 9216B doubles as P buffer
  __shared__ _Float16 Vs[128][72];     // V tile, d-major
  _Float16* Ps = &Ks[0][0];            // [4][16][72] alias

  const int tid  = threadIdx.x;
  const int lane = tid & 63;
  const int w    = tid >> 6;
  const int n16  = lane & 15;
  const int quad = lane >> 4;

  const int xb    = blockIdx.x;        // bh*4 + split
  const int qt    = blockIdx.y;
  const int split = xb & 3;
  const int bh    = xb >> 2;
  const int h = bh & 3, b = bh >> 2;

  const _Float16* Qg = Qh + (size_t)(b * LQ_ + qt * 64) * DM + h * HD_;
  const _Float16* Kg = Kh + (size_t)(b * LKV_) * DM + h * HD_;
  const _Float16* Vg = Vtg + (size_t)(bh * HD_) * LKV_;

  // stage Q (64x128) into Ks, pull A-frags to registers
#pragma unroll
  for (int i = 0; i < 4; ++i) {
    int f = i * 256 + tid;
    int r = f >> 4, c8 = (f & 15) * 8;
    *(half8*)&Ks[r][c8] = *(const half8*)(Qg + (size_t)r * DM + c8);
  }
  __syncthreads();
  half8 qf[4];
#pragma unroll
  for (int kc = 0; kc < 4; ++kc)
    qf[kc] = *(const half8*)&Ks[w * 16 + n16][kc * 32 + quad * 8];
  __syncthreads();

  floatx4 o[8];
#pragma unroll
  for (int vb = 0; vb < 8; ++vb) o[vb] = (floatx4){0.f, 0.f, 0.f, 0.f};
  float m_i[4] = {-INFINITY, -INFINITY, -INFINITY, -INFINITY};
  float l_i[4] = {0.f, 0.f, 0.f, 0.f};

  for (int kt = split * 16; kt < split * 16 + 16; ++kt) {
    // stage K tile (64 kv x 128 d) and V tile (128 d x 64 kv)
#pragma unroll
    for (int i = 0; i < 4; ++i) {
      int f = i * 256 + tid;
      int r = f >> 4, c8 = (f & 15) * 8;
      *(half8*)&Ks[r][c8] = *(const half8*)(Kg + (size_t)(kt * 64 + r) * DM + c8);
    }
#pragma unroll
    for (int i = 0; i < 4; ++i) {
      int f = i * 256 + tid;
      int d = f >> 3, kv8 = (f & 7) * 8;
      *(half8*)&Vs[d][kv8] = *(const half8*)(Vg + (size_t)d * LKV_ + kt * 64 + kv8);
    }
    __syncthreads();

    // S[16 x 64] per wave = Q K^T
    floatx4 s[4];
#pragma unroll
    for (int cb = 0; cb < 4; ++cb) {
      s[cb] = (floatx4){0.f, 0.f, 0.f, 0.f};
#pragma unroll
      for (int kc = 0; kc < 4; ++kc) {
        half8 kf = *(const half8*)&Ks[cb * 16 + n16][kc * 32 + quad * 8];
        s[cb] = MFMA16(qf[kc], kf, s[cb]);
      }
    }
    __syncthreads();   // all waves done reading Ks before P overwrites it

    // online softmax: rows r = quad*4 + reg, reduce across 16 lanes
    float alpha[4], rs[4];
#pragma unroll
    for (int r = 0; r < 4; ++r) {
      float m0 = fmaxf(fmaxf(s[0][r], s[1][r]), fmaxf(s[2][r], s[3][r]));
#pragma unroll
      for (int off = 1; off < 16; off <<= 1) m0 = fmaxf(m0, __shfl_xor(m0, off));
      float mn = fmaxf(m_i[r], m0);
      alpha[r] = __expf(m_i[r] - mn);
      m_i[r] = mn;
      rs[r] = 0.f;
    }
#pragma unroll
    for (int cb = 0; cb < 4; ++cb) {
#pragma unroll
      for (int r = 0; r < 4; ++r) {
        float p = __expf(s[cb][r] - m_i[r]);
        rs[r] += p;
        Ps[((w * 16) + quad * 4 + r) * 72 + cb * 16 + n16] = (_Float16)p;
      }
    }
#pragma unroll
    for (int r = 0; r < 4; ++r) {
      float t = rs[r];
#pragma unroll
      for (int off = 1; off < 16; off <<= 1) t += __shfl_xor(t, off);
      l_i[r] = l_i[r] * alpha[r] + t;
#pragma unroll
      for (int vb = 0; vb < 8; ++vb) o[vb][r] *= alpha[r];
    }

    // O += P V   (P from per-wave LDS slice; intra-wave)
    half8 pf[2];
#pragma unroll
    for (int kc = 0; kc < 2; ++kc)
      pf[kc] = *(const half8*)&Ps[(w * 16 + n16) * 72 + kc * 32 + quad * 8];
#pragma unroll
    for (int vb = 0; vb < 8; ++vb) {
#pragma unroll
      for (int kc = 0; kc < 2; ++kc) {
        half8 vf = *(const half8*)&Vs[vb * 16 + n16][kc * 32 + quad * 8];
        o[vb] = MFMA16(pf[kc], vf, o[vb]);
      }
    }
    __syncthreads();
  }

  // write unnormalized partial O (f16) and m,l
  _Float16* Og = Opart + ((size_t)xb * 1024 + qt * 64 + w * 16) * HD_;
#pragma unroll
  for (int r = 0; r < 4; ++r) {
#pragma unroll
    for (int vb = 0; vb < 8; ++vb)
      Og[(size_t)(quad * 4 + r) * HD_ + vb * 16 + n16] = (_Float16)o[vb][r];
  }
  if (n16 == 0) {
#pragma unroll
    for (int r = 0; r < 4; ++r) {
      size_t idx = ((size_t)xb * 1024 + qt * 64 + w * 16 + quad * 4 + r) * 2;
      ml[idx] = m_i[r]; ml[idx + 1] = l_i[r];
    }
  }
}

// ---------------------------------------------------------------------------
// Combine 4 KV-split partials -> CTXh f16 [B*LQ, 512]
// ---------------------------------------------------------------------------
__global__ __launch_bounds__(256) void combine_splits(
    const _Float16* __restrict__ Opart,
    const float* __restrict__ ml,
    _Float16* __restrict__ CTXh)
{
  int g  = blockIdx.x * 2 + (threadIdx.x >> 7);   // row 0..16383 (bh*1024+q)
  int d  = threadIdx.x & 127;
  int bh = g >> 10, q = g & 1023;
  int b = bh >> 2, h = bh & 3;

  float m[4], l[4], M = -INFINITY;
#pragma unroll
  for (int p = 0; p < 4; ++p) {
    size_t idx = ((size_t)(bh * 4 + p) * 1024 + q) * 2;
    m[p] = ml[idx]; l[p] = ml[idx + 1];
    M = fmaxf(M, m[p]);
  }
  float L = 0.f, o = 0.f;
#pragma unroll
  for (int p = 0; p < 4; ++p) {
    float wgt = __expf(m[p] - M);
    L += wgt * l[p];
    o += wgt * (float)Opart[((size_t)(bh * 4 + p) * 1024 + q) * HD_ + d];
  }
  CTXh[(size_t)(b * LQ_ + q) * DM + h * HD_ + d] = (_Float16)(o / L);
}

// ---------------------------------------------------------------------------
extern "C" void kernel_launch(void* const* d_in, const int* in_sizes, int n_in,
                              void* d_out, int out_size, void* d_ws, size_t ws_size,
                              hipStream_t stream) {
  const float* x   = (const float*)d_in[0];
  const float* enc = (const float*)d_in[1];
  const float* Wq  = (const float*)d_in[2];
  const float* Wk  = (const float*)d_in[3];
  const float* Wv  = (const float*)d_in[4];
  const float* bq  = (const float*)d_in[5];
  const float* bk  = (const float*)d_in[6];
  const float* bv  = (const float*)d_in[7];
  const float* Wo  = (const float*)d_in[8];
  const float* bo  = (const float*)d_in[9];
  float* out = (float*)d_out;

  // workspace layout (MB offsets):
  //   0  Qh    f16 [4096 x 512]        4 MB
  //   4  Kh    f16 [16384 x 512]      16 MB
  //  20  Vh    f16 [16384 x 512]      16 MB   (dead after transpose; Opart reuses)
  //  20  Opart f16 [64 x 1024 x 128]  16 MB
  //  36  Vtg   f16 [2048 x 4096]      16 MB
  //  52  ench  f16 [16384 x 512]      16 MB
  //  68  xh    f16 [4096 x 512]        4 MB
  //  72  Wh    f16 [4 x 512 x 512]     2 MB
  //  74  CTXh  f16 [4096 x 512]        4 MB
  //  78  ml    f32 [64 x 1024 x 2]     0.5 MB    (total 78.5 MB)
  char* ws = (char*)d_ws;
  _Float16* Qh    = (_Float16*)(ws);
  _Float16* Kh    = (_Float16*)(ws + (4u  << 20));
  _Float16* Vh    = (_Float16*)(ws + (20u << 20));
  _Float16* Opart = (_Float16*)(ws + (20u << 20));
  _Float16* Vtg   = (_Float16*)(ws + (36u << 20));
  _Float16* ench  = (_Float16*)(ws + (52u << 20));
  _Float16* xh    = (_Float16*)(ws + (68u << 20));
  _Float16* Wh    = (_Float16*)(ws + (72u << 20));
  _Float16* CTXh  = (_Float16*)(ws + (74u << 20));
  float*    mlp   = (float*)   (ws + (78u << 20));

  _Float16* Whq = Wh;
  _Float16* Whk = Wh + 262144;
  _Float16* Whv = Wh + 524288;
  _Float16* Who = Wh + 786432;

  const float qscale = 0.08838834764831845f;  // 1/sqrt(128)
  dim3 blk(256);

  cast_f32_f16<<<dim3(2048), blk, 0, stream>>>(x,   xh,   524288);
  cast_f32_f16<<<dim3(8192), blk, 0, stream>>>(enc, ench, 2097152);
  cast_weights<<<dim3(1024), blk, 0, stream>>>(Wq, Wk, Wv, Wo, Wh);

  proj_mfma<0><<<dim3(32, 4),  blk, 0, stream>>>(xh,   Whq, bq, Qh, qscale);
  proj_mfma<0><<<dim3(128, 4), blk, 0, stream>>>(ench, Whk, bk, Kh, 1.f);
  proj_mfma<0><<<dim3(128, 4), blk, 0, stream>>>(ench, Whv, bv, Vh, 1.f);

  transpose_v<<<dim3(64, 2, 16), blk, 0, stream>>>(Vh, Vtg);

  flash_mfma_split<<<dim3(64, 16), blk, 0, stream>>>(Qh, Kh, Vtg, Opart, mlp);

  combine_splits<<<dim3(8192), blk, 0, stream>>>(Opart, mlp, CTXh);

  proj_mfma<1><<<dim3(32, 4),  blk, 0, stream>>>(CTXh, Who, bo, out, 1.f);
}

// Round 5
// 229.580 us; speedup vs baseline: 5.0528x; 1.1356x over previous
//
#include <hip/hip_runtime.h>
#include <math.h>

// Problem constants
#define B_    4
#define LQ_   1024
#define LKV_  4096
#define DM    512    // model dim
#define NH    4
#define HD_   128    // head dim

typedef _Float16 half8   __attribute__((ext_vector_type(8)));
typedef _Float16 half4_t __attribute__((ext_vector_type(4)));
typedef float    floatx4 __attribute__((ext_vector_type(4)));

#define MFMA16(a, b, c) __builtin_amdgcn_mfma_f32_16x16x32_f16((a), (b), (c), 0, 0, 0)

// ---------------------------------------------------------------------------
// f16 MFMA GEMM with fused f32->f16 input cast.
//   Y[M,512] = (X[M,512] @ W[512,512]^T + bias) * scale
// MODE 0: f32 out row-major. MODE 1: f16 out row-major.
// MODE 2: f16 out transposed per-head to Vt[(b*4+by)*128 + d][LKV] (V path).
// Block 256 = 4 waves (2x2 of 64x64), tile 128x128, BK=64.
// A-frag: A[m=lane&15][k=quad*8+j]; B-frag: B[k=quad*8+j][n=lane&15]
// C/D:    row=quad*4+reg, col=lane&15
// ---------------------------------------------------------------------------
template<typename XT, int MODE>
__global__ __launch_bounds__(256) void proj_mfma(
    const XT* __restrict__ X,
    const float* __restrict__ W,
    const float* __restrict__ bias,
    void* __restrict__ Yv, float scale)
{
  __shared__ _Float16 SMEM[128 * 144];          // 36,864 B
  _Float16 (*Xs)[72] = (_Float16(*)[72])SMEM;
  _Float16 (*Ws)[72] = (_Float16(*)[72])(SMEM + 128 * 72);

  const int tid  = threadIdx.x;
  const int lane = tid & 63;
  const int w    = tid >> 6;
  const int n16  = lane & 15;
  const int quad = lane >> 4;
  const int wm   = (w & 1) * 64;
  const int wn   = (w >> 1) * 64;
  const int row0 = blockIdx.x * 128;
  const int col0 = blockIdx.y * 128;

  floatx4 acc[4][4];
#pragma unroll
  for (int a = 0; a < 4; ++a)
#pragma unroll
    for (int b = 0; b < 4; ++b) acc[a][b] = (floatx4){0.f, 0.f, 0.f, 0.f};

  for (int k0 = 0; k0 < 512; k0 += 64) {
#pragma unroll
    for (int i = 0; i < 4; ++i) {
      int c = i * 256 + tid;            // 0..1023
      int r = c >> 3, off = (c & 7) * 8;
      half8 hx;
      if (sizeof(XT) == 4) {
        const float* xp = (const float*)X + (size_t)(row0 + r) * 512 + k0 + off;
        float4 a = *(const float4*)xp, b2 = *(const float4*)(xp + 4);
        hx[0] = (_Float16)a.x;  hx[1] = (_Float16)a.y;
        hx[2] = (_Float16)a.z;  hx[3] = (_Float16)a.w;
        hx[4] = (_Float16)b2.x; hx[5] = (_Float16)b2.y;
        hx[6] = (_Float16)b2.z; hx[7] = (_Float16)b2.w;
      } else {
        hx = *(const half8*)((const _Float16*)X + (size_t)(row0 + r) * 512 + k0 + off);
      }
      *(half8*)&Xs[r][off] = hx;
      const float* wp = W + (size_t)(col0 + r) * 512 + k0 + off;
      float4 wa = *(const float4*)wp, wb = *(const float4*)(wp + 4);
      half8 hw;
      hw[0] = (_Float16)wa.x; hw[1] = (_Float16)wa.y;
      hw[2] = (_Float16)wa.z; hw[3] = (_Float16)wa.w;
      hw[4] = (_Float16)wb.x; hw[5] = (_Float16)wb.y;
      hw[6] = (_Float16)wb.z; hw[7] = (_Float16)wb.w;
      *(half8*)&Ws[r][off] = hw;
    }
    __syncthreads();
#pragma unroll
    for (int kc = 0; kc < 2; ++kc) {
      half8 af[4], bf[4];
#pragma unroll
      for (int mb = 0; mb < 4; ++mb)
        af[mb] = *(const half8*)&Xs[wm + mb * 16 + n16][kc * 32 + quad * 8];
#pragma unroll
      for (int nb = 0; nb < 4; ++nb)
        bf[nb] = *(const half8*)&Ws[wn + nb * 16 + n16][kc * 32 + quad * 8];
#pragma unroll
      for (int mb = 0; mb < 4; ++mb)
#pragma unroll
        for (int nb = 0; nb < 4; ++nb)
          acc[mb][nb] = MFMA16(af[mb], bf[nb], acc[mb][nb]);
    }
    __syncthreads();
  }

  if (MODE == 2) {
    // transpose epilogue: acc rows = kv, cols = d. Bounce through LDS.
    _Float16 (*Ts)[144] = (_Float16(*)[144])SMEM;
#pragma unroll
    for (int mb = 0; mb < 4; ++mb) {
#pragma unroll
      for (int nb = 0; nb < 4; ++nb) {
        int dl = wn + nb * 16 + n16;
        float bi = bias[col0 + dl];
        half4_t hv;
#pragma unroll
        for (int r = 0; r < 4; ++r) hv[r] = (_Float16)(acc[mb][nb][r] + bi);
        *(half4_t*)&Ts[dl][wm + mb * 16 + quad * 4] = hv;
      }
    }
    __syncthreads();
    int b   = row0 >> 12;        // row0 / 4096
    int kv0 = row0 & 4095;
    _Float16* Vt = (_Float16*)Yv;
    // 128 d x 128 kv = 2048 half8 stores -> 8 iterations of 256 threads
    // (round-4 bug: 4 iterations left d rows 64..127 unwritten)
#pragma unroll
    for (int i = 0; i < 8; ++i) {
      int f = i * 256 + tid;
      int dl = f >> 4, kv8 = (f & 15) * 8;
      half8 ov = *(const half8*)&Ts[dl][kv8];
      *(half8*)(Vt + (size_t)((b * 4 + blockIdx.y) * 128 + dl) * LKV_ + kv0 + kv8) = ov;
    }
  } else {
#pragma unroll
    for (int mb = 0; mb < 4; ++mb) {
#pragma unroll
      for (int nb = 0; nb < 4; ++nb) {
#pragma unroll
        for (int r = 0; r < 4; ++r) {
          int row = row0 + wm + mb * 16 + quad * 4 + r;
          int col = col0 + wn + nb * 16 + n16;
          float v = (acc[mb][nb][r] + bias[col]) * scale;
          if (MODE == 0) ((float*)Yv)[(size_t)row * 512 + col] = v;
          else ((_Float16*)Yv)[(size_t)row * 512 + col] = (_Float16)v;
        }
      }
    }
  }
}

// ---------------------------------------------------------------------------
// Flash attention, S^T form. Block = 4 waves x 32 q = 128 q rows, split-KV x4.
// S^T = K Q^T : A=K-frag (m=kv), B=Q-frag (n=q). C/D row=kv=quad*4+reg, col=q=n16
//   -> each lane holds 4 CONSECUTIVE kv for one q column: P stores are b64.
// PV: A=P (m=q,k=kv), B=V^T (k=kv,n=d); O C-layout row=q, col=d.
// ---------------------------------------------------------------------------
__global__ __launch_bounds__(256, 2) void flash_mfma2(
    const _Float16* __restrict__ Qh,   // [B*LQ, 512], pre-scaled
    const _Float16* __restrict__ Kh,   // [B*LKV, 512]
    const _Float16* __restrict__ Vtg,  // [B*NH*HD, LKV], d-major
    _Float16* __restrict__ Opart,      // [64][1024][128] f16 unnormalized
    float* __restrict__ ml)            // [64][1024][2]
{
  __shared__ _Float16 Ks[64][136];     // Q staging chunks, then K tiles
  __shared__ _Float16 Vs[128][72];     // V tile, d-major
  __shared__ _Float16 Ps[4][32][72];   // per-wave P (32 q x 64 kv)

  const int tid  = threadIdx.x;
  const int lane = tid & 63;
  const int w    = tid >> 6;
  const int n16  = lane & 15;
  const int quad = lane >> 4;

  const int xb    = blockIdx.x;        // bh*4 + split
  const int qt    = blockIdx.y;        // 0..7, 128 q each
  const int split = xb & 3;
  const int bh    = xb >> 2;
  const int h = bh & 3, b = bh >> 2;

  const _Float16* Qg = Qh + (size_t)(b * LQ_ + qt * 128) * DM + h * HD_;
  const _Float16* Kg = Kh + (size_t)(b * LKV_) * DM + h * HD_;
  const _Float16* Vg = Vtg + (size_t)(bh * HD_) * LKV_;

  // load Q frags for this wave (q = w*32 + qb*16 + n16) via 2 chunks through Ks
  half8 qf[2][4];
  const int chunk = w >> 1;
  const int qrb   = (w & 1) * 32;
#pragma unroll
  for (int c = 0; c < 2; ++c) {
#pragma unroll
    for (int i = 0; i < 4; ++i) {
      int f = i * 256 + tid;
      int r = f >> 4, c8 = (f & 15) * 8;
      *(half8*)&Ks[r][c8] = *(const half8*)(Qg + (size_t)(c * 64 + r) * DM + c8);
    }
    __syncthreads();
    if (chunk == c) {
#pragma unroll
      for (int qb = 0; qb < 2; ++qb)
#pragma unroll
        for (int kc = 0; kc < 4; ++kc)
          qf[qb][kc] = *(const half8*)&Ks[qrb + qb * 16 + n16][kc * 32 + quad * 8];
    }
    __syncthreads();
  }

  floatx4 o[2][8];
#pragma unroll
  for (int mb = 0; mb < 2; ++mb)
#pragma unroll
    for (int vb = 0; vb < 8; ++vb) o[mb][vb] = (floatx4){0.f, 0.f, 0.f, 0.f};
  float m_i[2] = {-INFINITY, -INFINITY};
  float l_i[2] = {0.f, 0.f};

  for (int kt = split * 16; kt < split * 16 + 16; ++kt) {
    // stage K (64 kv x 128 d) and V (128 d x 64 kv)
#pragma unroll
    for (int i = 0; i < 4; ++i) {
      int f = i * 256 + tid;
      int r = f >> 4, c8 = (f & 15) * 8;
      *(half8*)&Ks[r][c8] = *(const half8*)(Kg + (size_t)(kt * 64 + r) * DM + c8);
    }
#pragma unroll
    for (int i = 0; i < 4; ++i) {
      int f = i * 256 + tid;
      int d = f >> 3, kv8 = (f & 7) * 8;
      *(half8*)&Vs[d][kv8] = *(const half8*)(Vg + (size_t)d * LKV_ + kt * 64 + kv8);
    }
    __syncthreads();

    // S^T per wave: s[qb][cb], rows kv=cb*16+quad*4+r, col q=qb*16+n16
    floatx4 s[2][4];
#pragma unroll
    for (int qb = 0; qb < 2; ++qb)
#pragma unroll
      for (int cb = 0; cb < 4; ++cb) s[qb][cb] = (floatx4){0.f, 0.f, 0.f, 0.f};
#pragma unroll
    for (int cb = 0; cb < 4; ++cb) {
#pragma unroll
      for (int kc = 0; kc < 4; ++kc) {
        half8 kf = *(const half8*)&Ks[cb * 16 + n16][kc * 32 + quad * 8];
        s[0][cb] = MFMA16(kf, qf[0][kc], s[0][cb]);
        s[1][cb] = MFMA16(kf, qf[1][kc], s[1][cb]);
      }
    }

    // online softmax per q column; reduce across quads (xor 16, 32)
    float alpha[2];
#pragma unroll
    for (int qb = 0; qb < 2; ++qb) {
      float mx = -INFINITY;
#pragma unroll
      for (int cb = 0; cb < 4; ++cb)
#pragma unroll
        for (int r = 0; r < 4; ++r) mx = fmaxf(mx, s[qb][cb][r]);
      mx = fmaxf(mx, __shfl_xor(mx, 16));
      mx = fmaxf(mx, __shfl_xor(mx, 32));
      float mn = fmaxf(m_i[qb], mx);
      alpha[qb] = __expf(m_i[qb] - mn);
      m_i[qb] = mn;
      float rs = 0.f;
#pragma unroll
      for (int cb = 0; cb < 4; ++cb) {
        half4_t ph;
#pragma unroll
        for (int r = 0; r < 4; ++r) {
          float p = __expf(s[qb][cb][r] - mn);
          rs += p;
          ph[r] = (_Float16)p;
        }
        *(half4_t*)&Ps[w][qb * 16 + n16][cb * 16 + quad * 4] = ph;
      }
      rs += __shfl_xor(rs, 16);
      rs += __shfl_xor(rs, 32);
      l_i[qb] = l_i[qb] * alpha[qb] + rs;
    }

    // rescale O: row q = mb*16 + quad*4 + r -> broadcast alpha from lane n16=quad*4+r
#pragma unroll
    for (int mb = 0; mb < 2; ++mb) {
#pragma unroll
      for (int r = 0; r < 4; ++r) {
        float a = __shfl(alpha[mb], (lane & 48) | (quad * 4 + r));
#pragma unroll
        for (int vb = 0; vb < 8; ++vb) o[mb][vb][r] *= a;
      }
    }

    // O += P V  (P A-frags from per-wave LDS; intra-wave ordering, no barrier)
    half8 pf[2][2];
#pragma unroll
    for (int mb = 0; mb < 2; ++mb)
#pragma unroll
      for (int kc = 0; kc < 2; ++kc)
        pf[mb][kc] = *(const half8*)&Ps[w][mb * 16 + n16][kc * 32 + quad * 8];
#pragma unroll
    for (int vb = 0; vb < 8; ++vb) {
#pragma unroll
      for (int kc = 0; kc < 2; ++kc) {
        half8 vf = *(const half8*)&Vs[vb * 16 + n16][kc * 32 + quad * 8];
        o[0][vb] = MFMA16(pf[0][kc], vf, o[0][vb]);
        o[1][vb] = MFMA16(pf[1][kc], vf, o[1][vb]);
      }
    }
    __syncthreads();
  }

  // write unnormalized partial O (f16) and (m,l)
  _Float16* Og = Opart + ((size_t)xb * 1024 + qt * 128 + w * 32) * HD_;
#pragma unroll
  for (int mb = 0; mb < 2; ++mb) {
#pragma unroll
    for (int r = 0; r < 4; ++r) {
#pragma unroll
      for (int vb = 0; vb < 8; ++vb)
        Og[(size_t)(mb * 16 + quad * 4 + r) * HD_ + vb * 16 + n16] =
            (_Float16)o[mb][vb][r];
    }
  }
  if (quad == 0) {
#pragma unroll
    for (int qb = 0; qb < 2; ++qb) {
      size_t qi = (size_t)xb * 1024 + qt * 128 + w * 32 + qb * 16 + n16;
      ml[qi * 2] = m_i[qb];
      ml[qi * 2 + 1] = l_i[qb];
    }
  }
}

// ---------------------------------------------------------------------------
// Combine 4 KV-split partials -> CTXh f16 [B*LQ, 512]
// ---------------------------------------------------------------------------
__global__ __launch_bounds__(256) void combine_splits(
    const _Float16* __restrict__ Opart,
    const float* __restrict__ ml,
    _Float16* __restrict__ CTXh)
{
  int g  = blockIdx.x * 2 + (threadIdx.x >> 7);   // row 0..16383 (bh*1024+q)
  int d  = threadIdx.x & 127;
  int bh = g >> 10, q = g & 1023;
  int b = bh >> 2, h = bh & 3;

  float m[4], l[4], M = -INFINITY;
#pragma unroll
  for (int p = 0; p < 4; ++p) {
    size_t idx = ((size_t)(bh * 4 + p) * 1024 + q) * 2;
    m[p] = ml[idx]; l[p] = ml[idx + 1];
    M = fmaxf(M, m[p]);
  }
  float L = 0.f, o = 0.f;
#pragma unroll
  for (int p = 0; p < 4; ++p) {
    float wgt = __expf(m[p] - M);
    L += wgt * l[p];
    o += wgt * (float)Opart[((size_t)(bh * 4 + p) * 1024 + q) * HD_ + d];
  }
  CTXh[(size_t)(b * LQ_ + q) * DM + h * HD_ + d] = (_Float16)(o / L);
}

// ---------------------------------------------------------------------------
extern "C" void kernel_launch(void* const* d_in, const int* in_sizes, int n_in,
                              void* d_out, int out_size, void* d_ws, size_t ws_size,
                              hipStream_t stream) {
  const float* x   = (const float*)d_in[0];
  const float* enc = (const float*)d_in[1];
  const float* Wq  = (const float*)d_in[2];
  const float* Wk  = (const float*)d_in[3];
  const float* Wv  = (const float*)d_in[4];
  const float* bq  = (const float*)d_in[5];
  const float* bk  = (const float*)d_in[6];
  const float* bv  = (const float*)d_in[7];
  const float* Wo  = (const float*)d_in[8];
  const float* bo  = (const float*)d_in[9];
  float* out = (float*)d_out;

  // workspace layout (MB offsets):
  //   0  Qh    f16 [4096 x 512]        4 MB
  //   4  Kh    f16 [16384 x 512]      16 MB
  //  20  Vtg   f16 [2048 x 4096]      16 MB   (V written transposed by proj)
  //  36  Opart f16 [64 x 1024 x 128]  16 MB
  //  52  CTXh  f16 [4096 x 512]        4 MB
  //  56  ml    f32 [64 x 1024 x 2]     0.5 MB    (total 56.5 MB)
  char* ws = (char*)d_ws;
  _Float16* Qh    = (_Float16*)(ws);
  _Float16* Kh    = (_Float16*)(ws + (4u  << 20));
  _Float16* Vtg   = (_Float16*)(ws + (20u << 20));
  _Float16* Opart = (_Float16*)(ws + (36u << 20));
  _Float16* CTXh  = (_Float16*)(ws + (52u << 20));
  float*    mlp   = (float*)   (ws + (56u << 20));

  const float qscale = 0.08838834764831845f;  // 1/sqrt(128)
  dim3 blk(256);

  proj_mfma<float, 1><<<dim3(32, 4),  blk, 0, stream>>>(x,   Wq, bq, Qh,  qscale);
  proj_mfma<float, 1><<<dim3(128, 4), blk, 0, stream>>>(enc, Wk, bk, Kh,  1.f);
  proj_mfma<float, 2><<<dim3(128, 4), blk, 0, stream>>>(enc, Wv, bv, Vtg, 1.f);

  flash_mfma2<<<dim3(64, 8), blk, 0, stream>>>(Qh, Kh, Vtg, Opart, mlp);

  combine_splits<<<dim3(8192), blk, 0, stream>>>(Opart, mlp, CTXh);

  proj_mfma<_Float16, 0><<<dim3(32, 4), blk, 0, stream>>>(CTXh, Wo, bo, out, 1.f);
}